// Round 1
// baseline (144.149 us; speedup 1.0000x reference)
//
#include <hip/hip_runtime.h>
#include <math.h>

#define NPTS 131072
#define DDIM 64
#define KMIX 64

// log(2*pi)
#define LOG_2PI 1.8378770664093453f

// ---------------------------------------------------------------------------
// Prep kernel: 1 block, 64 threads (thread = mixture component k).
// Builds transposed coefficient arrays At[d][k], Bt[d][k] and per-k constant C[k].
//   weighted[k,n] = sum_d ( x^2 * At[d][k] + x * Bt[d][k] ) + C[k]
// ---------------------------------------------------------------------------
__global__ void gmm_prep(const float* __restrict__ mu,
                         const float* __restrict__ lv,
                         const float* __restrict__ lp,
                         float* __restrict__ At,   // [DDIM][KMIX]
                         float* __restrict__ Bt,   // [DDIM][KMIX]
                         float* __restrict__ C)    // [KMIX]
{
    const int k = threadIdx.x;  // 0..63

    // logsumexp over logpriors (single wave of 64)
    float x = lp[k];
    float m = x;
    #pragma unroll
    for (int off = 32; off > 0; off >>= 1)
        m = fmaxf(m, __shfl_xor(m, off, 64));
    float s = expf(x - m);
    #pragma unroll
    for (int off = 32; off > 0; off >>= 1)
        s += __shfl_xor(s, off, 64);
    const float lse_lp = m + logf(s);

    float c = (x - lse_lp) - 0.5f * (float)DDIM * LOG_2PI;

    for (int d = 0; d < DDIM; ++d) {
        const float l  = lv[k * DDIM + d];
        const float a  = expf(-l);            // inverse variance
        const float mv = mu[k * DDIM + d];
        At[d * KMIX + k] = -0.5f * a;
        Bt[d * KMIX + k] = mv * a;
        c += -0.5f * l - 0.5f * mv * mv * a;
    }
    C[k] = c;
}

// ---------------------------------------------------------------------------
// Main kernel: one thread per example n. Each thread accumulates the full
// K=64 column in registers, so the logsumexp over K is thread-local (no LDS,
// no shuffles), and stores are coalesced across threads for each k-row.
// Inner loop: 2 FMAs per (d,k); coefficient loads are wave-uniform
// (loop-index addressing into __restrict__ const arrays) -> SMEM s_loads,
// each FMA uses at most 1 scalar operand.
// ---------------------------------------------------------------------------
__global__ __launch_bounds__(256)
void gmm_main(const float* __restrict__ xg,
              const float* __restrict__ At,
              const float* __restrict__ Bt,
              const float* __restrict__ C,
              float* __restrict__ out)
{
    const int n = blockIdx.x * 256 + threadIdx.x;

    float acc[KMIX];
    #pragma unroll
    for (int k = 0; k < KMIX; ++k) acc[k] = 0.0f;

    const float* xrow = xg + (size_t)n * DDIM;

    #pragma unroll 1
    for (int dc = 0; dc < DDIM; dc += 8) {
        const float4 xa = *(const float4*)(xrow + dc);
        const float4 xb = *(const float4*)(xrow + dc + 4);
        float xs[8] = {xa.x, xa.y, xa.z, xa.w, xb.x, xb.y, xb.z, xb.w};

        #pragma unroll
        for (int dd = 0; dd < 8; ++dd) {
            const int d = dc + dd;
            const float xv = xs[dd];
            const float x2 = xv * xv;
            const float* __restrict__ Ar = At + d * KMIX;
            const float* __restrict__ Br = Bt + d * KMIX;
            #pragma unroll
            for (int k = 0; k < KMIX; ++k) {
                acc[k] = fmaf(x2, Ar[k], acc[k]);
                acc[k] = fmaf(xv, Br[k], acc[k]);
            }
        }
    }

    // add per-k constant, then logsumexp over k (thread-local)
    float m = -INFINITY;
    #pragma unroll
    for (int k = 0; k < KMIX; ++k) {
        acc[k] += C[k];
        m = fmaxf(m, acc[k]);
    }
    float s = 0.0f;
    #pragma unroll
    for (int k = 0; k < KMIX; ++k) s += __expf(acc[k] - m);
    const float lse = m + __logf(s);

    #pragma unroll
    for (int k = 0; k < KMIX; ++k) {
        out[(size_t)k * NPTS + n] = acc[k] - lse;
    }
}

extern "C" void kernel_launch(void* const* d_in, const int* in_sizes, int n_in,
                              void* d_out, int out_size, void* d_ws, size_t ws_size,
                              hipStream_t stream) {
    const float* inputs    = (const float*)d_in[0];  // (N, D)
    const float* mu        = (const float*)d_in[1];  // (K, D)
    const float* logvars   = (const float*)d_in[2];  // (K, D)
    const float* logpriors = (const float*)d_in[3];  // (K,)

    float* out = (float*)d_out;                       // (K, N)

    // workspace layout: At[D*K] | Bt[D*K] | C[K]
    float* At = (float*)d_ws;
    float* Bt = At + DDIM * KMIX;
    float* Cc = Bt + DDIM * KMIX;

    gmm_prep<<<1, KMIX, 0, stream>>>(mu, logvars, logpriors, At, Bt, Cc);
    gmm_main<<<NPTS / 256, 256, 0, stream>>>(inputs, At, Bt, Cc, out);
}